// Round 4
// baseline (222.704 us; speedup 1.0000x reference)
//
#include <hip/hip_runtime.h>
#include <stdint.h>

typedef __attribute__((ext_vector_type(8))) short short8v;    // 8 x bf16 (raw bits)
typedef __attribute__((ext_vector_type(4))) short short4v;    // 4 x bf16
typedef __attribute__((ext_vector_type(4))) float float4v;    // MFMA C/D
typedef __attribute__((ext_vector_type(4))) unsigned short ushort4v;
typedef __attribute__((ext_vector_type(4))) float floatvec4;
typedef __attribute__((ext_vector_type(2))) unsigned int uint2v;

#define DEVI __device__ __forceinline__

// fp32 -> bf16 round-to-nearest-even (finite inputs only)
DEVI unsigned short f2bf(float f) {
    unsigned int u = __builtin_bit_cast(unsigned int, f);
    u += 0x7FFFu + ((u >> 16) & 1u);
    return (unsigned short)(u >> 16);
}

// pack 2 fp32 -> 2 bf16 in one u32 (low = a)
DEVI unsigned int pk2bf(float a, float b) {
#if defined(__has_builtin) && __has_builtin(__builtin_amdgcn_cvt_pk_bf16_f32)
    auto r = __builtin_amdgcn_cvt_pk_bf16_f32(a, b);
    unsigned int u;
    __builtin_memcpy(&u, &r, 4);
    return u;
#else
    return (unsigned int)f2bf(a) | ((unsigned int)f2bf(b) << 16);
#endif
}

DEVI float ex2(float x) {
#if defined(__has_builtin) && __has_builtin(__builtin_amdgcn_exp2f)
    return __builtin_amdgcn_exp2f(x);
#else
    return __builtin_exp2f(x);
#endif
}

typedef __attribute__((address_space(1))) void GV;
typedef __attribute__((address_space(3))) void LV;
// async global->LDS, 16B per lane; LDS dest = wave-uniform base + lane*16
DEVI void gl2lds16(const void* g, void* l) {
    __builtin_amdgcn_global_load_lds((GV*)g, (LV*)l, 16, 0, 0);
}

// ---------------------------------------------------------------------------
// x fp32 -> bf16  (exact-size grid, 4 elems/thread)
__global__ void conv_x_kernel(const float* __restrict__ x, unsigned short* __restrict__ xb) {
    const int i = (blockIdx.x * 256 + threadIdx.x) * 4;
    const floatvec4 v = *(const floatvec4*)&x[i];
    ushort4v o;
#pragma unroll
    for (int r = 0; r < 4; r++) o[r] = f2bf(v[r]);
    *(ushort4v*)&xb[i] = o;
}

// All 4 weight transposes in one launch: W [1024 k][1024 n] fp32 -> Wt [n][k] bf16
__global__ void transpose_w4(const float* __restrict__ W0, const float* __restrict__ W1,
                             const float* __restrict__ W2, const float* __restrict__ W3,
                             unsigned short* __restrict__ D0, unsigned short* __restrict__ D1,
                             unsigned short* __restrict__ D2, unsigned short* __restrict__ D3) {
    __shared__ float t[32][33];
    const int tx = threadIdx.x, ty = threadIdx.y;  // (32,8)
    const int bx = blockIdx.x, by = blockIdx.y, z = blockIdx.z;
    const float* W = (z == 0) ? W0 : (z == 1) ? W1 : (z == 2) ? W2 : W3;
    unsigned short* D = (z == 0) ? D0 : (z == 1) ? D1 : (z == 2) ? D2 : D3;
#pragma unroll
    for (int i = 0; i < 4; i++)
        t[ty + i * 8][tx] = W[(size_t)(by * 32 + ty + i * 8) * 1024 + bx * 32 + tx];
    __syncthreads();
#pragma unroll
    for (int i = 0; i < 4; i++)
        D[(size_t)(bx * 32 + ty + i * 8) * 1024 + by * 32 + tx] = f2bf(t[tx][ty + i * 8]);
}

// ---------------------------------------------------------------------------
// Fused QKV GEMM: C[4096 tok][1024] = Xbf @ W{q,k,v}t^T (+bias).
__global__ __launch_bounds__(256, 3) void qkv_gemm(
    const unsigned short* __restrict__ X, const unsigned short* __restrict__ Wt,
    const float* __restrict__ bq, const float* __restrict__ bk, const float* __restrict__ bv,
    unsigned short* __restrict__ qb, unsigned short* __restrict__ kb,
    unsigned short* __restrict__ vtb)
{
    __shared__ __align__(16) unsigned short As[128 * 32];
    __shared__ __align__(16) unsigned short Bs[128 * 32];
    const int tid = threadIdx.x, lane = tid & 63, wv = tid >> 6;
    const int quad = lane >> 4, l16 = lane & 15;
    const int w = blockIdx.x >> 3;
    const int n0 = (blockIdx.x & 7) * 128;
    const int row0 = blockIdx.y * 128;
    const unsigned short* Wsel = Wt + (size_t)w * (1024 * 1024);

    const int srow = lane >> 2;
    const int sg = (lane & 3) ^ ((lane >> 2) & 3) ^ ((lane >> 4) & 3);
    const int scol = sg * 8;
    const int fsw = (l16 & 3) ^ ((l16 >> 2) & 3);
    const int wm = (wv >> 1) * 64, wn = (wv & 1) * 64;

    float4v acc[4][4];
#pragma unroll
    for (int i = 0; i < 4; i++)
#pragma unroll
        for (int j = 0; j < 4; j++) acc[i][j] = (float4v){0.f, 0.f, 0.f, 0.f};

    for (int k0 = 0; k0 < 1024; k0 += 32) {
        __syncthreads();
#pragma unroll
        for (int i = 0; i < 2; i++) {
            const int c = wv * 2 + i;
            gl2lds16(X + (size_t)(row0 + c * 16 + srow) * 1024 + k0 + scol, As + c * 512);
            gl2lds16(Wsel + (size_t)(n0 + c * 16 + srow) * 1024 + k0 + scol, Bs + c * 512);
        }
        __syncthreads();
        short8v a[4], b[4];
#pragma unroll
        for (int mt = 0; mt < 4; mt++)
            a[mt] = *(const short8v*)&As[(wm + mt * 16 + l16) * 32 + ((quad ^ fsw) * 8)];
#pragma unroll
        for (int nt = 0; nt < 4; nt++)
            b[nt] = *(const short8v*)&Bs[(wn + nt * 16 + l16) * 32 + ((quad ^ fsw) * 8)];
#pragma unroll
        for (int mt = 0; mt < 4; mt++)
#pragma unroll
            for (int nt = 0; nt < 4; nt++)
                acc[mt][nt] = __builtin_amdgcn_mfma_f32_16x16x32_bf16(a[mt], b[nt], acc[mt][nt], 0, 0, 0);
    }

    const float* bias = (w == 0) ? bq : (w == 1) ? bk : bv;
    // q scale: 1/sqrt(64) * log2(e)  -> attention uses exp2 with no max-subtract
    const float scl = (w == 0) ? 0.18033688011112042f : 1.0f;
#pragma unroll
    for (int nt = 0; nt < 4; nt++) {
        const int col = n0 + wn + nt * 16 + l16;
        const float bb = bias[col];
        const int h = col >> 6, hd = col & 63;
#pragma unroll
        for (int mt = 0; mt < 4; mt++) {
            const int tok0 = row0 + wm + mt * 16 + quad * 4;
            const int b_ = tok0 >> 11, s0 = tok0 & 2047;
            if (w == 2) {
                ushort4v pk;
#pragma unroll
                for (int r = 0; r < 4; r++) pk[r] = f2bf(acc[mt][nt][r] + bb);
                *(ushort4v*)&vtb[(((size_t)b_ * 16 + h) * 64 + hd) * 2048 + s0] = pk;
            } else {
                unsigned short* dst = (w == 0) ? qb : kb;
#pragma unroll
                for (int r = 0; r < 4; r++)
                    dst[(((size_t)b_ * 16 + h) * 2048 + (s0 + r)) * 64 + hd] =
                        f2bf((acc[mt][nt][r] + bb) * scl);
            }
        }
    }
}

// ---------------------------------------------------------------------------
// Flash attention, S^T formulation, per-kc fused PV, IN-BLOCK SPLIT-K.
// 512 threads = 8 waves. Waves 0-3 (grp 0): keys 0-1023; waves 4-7 (grp 1):
// keys 1024-2047. Same 128 queries (wave gw owns 32). Exact additive combine
// (no max-subtract) via LDS at the end.
__global__ __launch_bounds__(512, 4) void attn_kernel(
    const unsigned short* __restrict__ qb, const unsigned short* __restrict__ kb,
    const unsigned short* __restrict__ vtb, unsigned short* __restrict__ ctxb)
{
    __shared__ __align__(16) unsigned short Kt[2][128 * 64];
    __shared__ __align__(16) unsigned short Vt[2][64 * 128];
    __shared__ __align__(16) unsigned short Pbs[8][32 * 32];
    const int tid = threadIdx.x, lane = tid & 63, wv = tid >> 6;  // 0..7
    const int grp = wv >> 2, gw = wv & 3;
    const int quad = lane >> 4, l16 = lane & 15;
    const int bh = blockIdx.x, qt = blockIdx.y;
    const size_t boff = (size_t)bh * (2048 * 64);
    const unsigned short* qp = qb + boff;
    const unsigned short* kp = kb + boff;
    const unsigned short* vp = vtb + boff;
    const int q0 = qt * 128 + gw * 32;

    // Q fragments (B operand): [q=l16][hd=quad*8..], register-resident
    short8v qf[2][2];
#pragma unroll
    for (int nt = 0; nt < 2; nt++)
#pragma unroll
        for (int kc = 0; kc < 2; kc++)
            qf[nt][kc] = *(const short8v*)&qp[(size_t)(q0 + nt * 16 + l16) * 64 + kc * 32 + quad * 8];

    float4v accO[2][4];
#pragma unroll
    for (int nt = 0; nt < 2; nt++)
#pragma unroll
        for (int ht = 0; ht < 4; ht++) accO[nt][ht] = (float4v){0.f, 0.f, 0.f, 0.f};
    float lsum[2] = {0.f, 0.f};

    // staging lane mapping (verified R1-R3)
    const int krow = lane >> 3;
    const int kg = (lane & 7) ^ (lane >> 3);
    const int vrow = lane >> 4;
    const int rsw = l16 & 7;

    // Kt A-frag read bases (row=key=mt*16+l16)
    const int ktb0 = l16 * 64 + ((quad ^ rsw) * 8);
    const int ktb1 = l16 * 64 + (((4 + quad) ^ rsw) * 8);
    // Vt B-frag read base: granule (kc*4+quad) ^ l16
    const int vrb = l16 * 128 + ((quad ^ (l16 & 3)) * 8);
    const int l12e = (l16 & 12) * 8;
    // Pbs write: chunk c = h*4+quad, c_phys = c ^ ((l16>>1)&7)
    const int pwb = l16 * 32 + ((quad ^ ((l16 >> 1) & 3)) * 4);
    const int hsw = (l16 >> 3) & 1;
    // Pbs read: chunks quad*2+t, c_phys = (quad*2+t) ^ ((l16>>1)&7)
    const int s1 = (l16 >> 1) & 1;
    const int prbase = l16 * 32 + ((quad ^ ((l16 >> 2) & 3)) * 8);
    const int pr0 = prbase + s1 * 4;
    const int pr1 = prbase + (1 - s1) * 4;

    unsigned short* KtL = Kt[grp];
    unsigned short* VtL = Vt[grp];
    const int ktbase = grp * 1024;

    for (int t = 0; t < 8; t++) {
        const int kt0 = ktbase + t * 128;
        __syncthreads();
#pragma unroll
        for (int i = 0; i < 4; i++) {
            const int c = gw * 4 + i;
            gl2lds16(kp + (size_t)(kt0 + c * 8 + krow) * 64 + kg * 8, KtL + c * 512);
            const int vr = c * 4 + vrow;
            const int vg = (lane & 15) ^ (vr & 15);
            gl2lds16(vp + (size_t)vr * 2048 + kt0 + vg * 8, VtL + c * 512);
        }
        __syncthreads();

#pragma unroll
        for (int kc = 0; kc < 4; kc++) {
            // ---- S phase for 32 keys (mt = kc*2+h), fused exp2 + P chunk write
#pragma unroll
            for (int h = 0; h < 2; h++) {
                const int mt = kc * 2 + h;
                const short8v a0 = *(const short8v*)&KtL[ktb0 + mt * 1024];
                const short8v a1 = *(const short8v*)&KtL[ktb1 + mt * 1024];
                const int hoff = (h ^ hsw) * 16;
#pragma unroll
                for (int nt = 0; nt < 2; nt++) {
                    float4v z = (float4v){0.f, 0.f, 0.f, 0.f};
                    z = __builtin_amdgcn_mfma_f32_16x16x32_bf16(a0, qf[nt][0], z, 0, 0, 0);
                    z = __builtin_amdgcn_mfma_f32_16x16x32_bf16(a1, qf[nt][1], z, 0, 0, 0);
                    const float p0 = ex2(z[0]), p1 = ex2(z[1]);
                    const float p2 = ex2(z[2]), p3 = ex2(z[3]);
                    lsum[nt] += (p0 + p1) + (p2 + p3);
                    *(uint2v*)&Pbs[wv][pwb + hoff + nt * 512] =
                        (uint2v){pk2bf(p0, p1), pk2bf(p2, p3)};
                }
            }
            // ---- V B-frags for this kc (issued before the P drain)
            short8v bvv[4];
            const int roff = (kc * 32) ^ l12e;
#pragma unroll
            for (int ht = 0; ht < 4; ht++)
                bvv[ht] = *(const short8v*)&VtL[vrb + roff + ht * 2048];
            asm volatile("s_waitcnt lgkmcnt(0)" ::: "memory");  // own P writes visible
            // ---- PV for this kc
#pragma unroll
            for (int nt = 0; nt < 2; nt++) {
                const short4v d0 = *(const short4v*)&Pbs[wv][pr0 + nt * 512];
                const short4v d1 = *(const short4v*)&Pbs[wv][pr1 + nt * 512];
                const short8v ap = __builtin_shufflevector(d0, d1, 0, 1, 2, 3, 4, 5, 6, 7);
#pragma unroll
                for (int ht = 0; ht < 4; ht++)
                    accO[nt][ht] = __builtin_amdgcn_mfma_f32_16x16x32_bf16(ap, bvv[ht], accO[nt][ht], 0, 0, 0);
            }
        }
    }

    // reduce row-sums across quads (query = l16 per nt) -- within wave
#pragma unroll
    for (int nt = 0; nt < 2; nt++) {
        lsum[nt] += __shfl_xor(lsum[nt], 16);
        lsum[nt] += __shfl_xor(lsum[nt], 32);
    }

    // ---- cross-group combine (exact: partial sums are additive) ----
    __syncthreads();
    float* Ob = (float*)&Kt[0][0];        // 4 x (32q x stride 68) fp32 = 34816B (fits Kt+Vt)
    float* Lb = (float*)&Pbs[0][0];       // 4 x 32 fp32
    if (grp == 1) {
        float* dst = Ob + gw * (32 * 68);
#pragma unroll
        for (int nt = 0; nt < 2; nt++) {
#pragma unroll
            for (int ht = 0; ht < 4; ht++)
#pragma unroll
                for (int r = 0; r < 4; r++)
                    dst[(nt * 16 + quad * 4 + r) * 68 + ht * 16 + l16] = accO[nt][ht][r];
            if (quad == 0) Lb[gw * 32 + nt * 16 + l16] = lsum[nt];
        }
    }
    __syncthreads();
    if (grp == 0) {
        const float* src = Ob + gw * (32 * 68);
        const int b_ = bh >> 4, h = bh & 15;
#pragma unroll
        for (int nt = 0; nt < 2; nt++) {
            lsum[nt] += Lb[gw * 32 + nt * 16 + l16];
#pragma unroll
            for (int ht = 0; ht < 4; ht++)
#pragma unroll
                for (int r = 0; r < 4; r++)
                    accO[nt][ht][r] += src[(nt * 16 + quad * 4 + r) * 68 + ht * 16 + l16];
        }
#pragma unroll
        for (int nt = 0; nt < 2; nt++)
#pragma unroll
            for (int r = 0; r < 4; r++) {
                const int s = q0 + nt * 16 + quad * 4 + r;
                const float inv = 1.0f / __shfl(lsum[nt], quad * 4 + r);
#pragma unroll
                for (int ht = 0; ht < 4; ht++) {
                    const int hd = ht * 16 + l16;
                    ctxb[((size_t)(b_ * 2048 + s)) * 1024 + h * 64 + hd] = f2bf(accO[nt][ht][r] * inv);
                }
            }
    }
}

// ---------------------------------------------------------------------------
// out = ctx @ Wo + bo  (fp32 output). 64x128 tile, wave = 32m x 64n.
__global__ __launch_bounds__(256, 4) void out_gemm(
    const unsigned short* __restrict__ ctx, const unsigned short* __restrict__ Wot,
    const float* __restrict__ bo, float* __restrict__ out)
{
    __shared__ __align__(16) unsigned short As[64 * 32];
    __shared__ __align__(16) unsigned short Bs[128 * 32];
    const int tid = threadIdx.x, lane = tid & 63, wv = tid >> 6;
    const int quad = lane >> 4, l16 = lane & 15;
    const int n0 = blockIdx.x * 128;
    const int row0 = blockIdx.y * 64;

    const int srow = lane >> 2;
    const int sg = (lane & 3) ^ ((lane >> 2) & 3) ^ ((lane >> 4) & 3);
    const int scol = sg * 8;
    const int fsw = (l16 & 3) ^ ((l16 >> 2) & 3);
    const int wm = (wv & 1) * 32, wn = (wv >> 1) * 64;

    float4v acc[2][4];
#pragma unroll
    for (int i = 0; i < 2; i++)
#pragma unroll
        for (int j = 0; j < 4; j++) acc[i][j] = (float4v){0.f, 0.f, 0.f, 0.f};

    for (int k0 = 0; k0 < 1024; k0 += 32) {
        __syncthreads();
#pragma unroll
        for (int i = 0; i < 3; i++) {
            const int idx = wv * 3 + i;   // 0..11: 4 As chunks then 8 Bs chunks
            if (idx < 4)
                gl2lds16(ctx + (size_t)(row0 + idx * 16 + srow) * 1024 + k0 + scol, As + idx * 512);
            else
                gl2lds16(Wot + (size_t)(n0 + (idx - 4) * 16 + srow) * 1024 + k0 + scol,
                         Bs + (idx - 4) * 512);
        }
        __syncthreads();
        short8v a[2], b[4];
#pragma unroll
        for (int mt = 0; mt < 2; mt++)
            a[mt] = *(const short8v*)&As[(wm + mt * 16 + l16) * 32 + ((quad ^ fsw) * 8)];
#pragma unroll
        for (int nt = 0; nt < 4; nt++)
            b[nt] = *(const short8v*)&Bs[(wn + nt * 16 + l16) * 32 + ((quad ^ fsw) * 8)];
#pragma unroll
        for (int mt = 0; mt < 2; mt++)
#pragma unroll
            for (int nt = 0; nt < 4; nt++)
                acc[mt][nt] = __builtin_amdgcn_mfma_f32_16x16x32_bf16(a[mt], b[nt], acc[mt][nt], 0, 0, 0);
    }

#pragma unroll
    for (int nt = 0; nt < 4; nt++) {
        const int col = n0 + wn + nt * 16 + l16;
        const float bb = bo[col];
#pragma unroll
        for (int mt = 0; mt < 2; mt++) {
            const int tok0 = row0 + wm + mt * 16 + quad * 4;
#pragma unroll
            for (int r = 0; r < 4; r++)
                out[(size_t)(tok0 + r) * 1024 + col] = acc[mt][nt][r] + bb;
        }
    }
}

// ---------------------------------------------------------------------------
extern "C" void kernel_launch(void* const* d_in, const int* in_sizes, int n_in,
                              void* d_out, int out_size, void* d_ws, size_t ws_size,
                              hipStream_t stream) {
    const float* x  = (const float*)d_in[0];
    const float* Wq = (const float*)d_in[1];
    const float* bq = (const float*)d_in[2];
    const float* Wk = (const float*)d_in[3];
    const float* bk = (const float*)d_in[4];
    const float* Wv = (const float*)d_in[5];
    const float* bv = (const float*)d_in[6];
    const float* Wo = (const float*)d_in[7];
    const float* bo = (const float*)d_in[8];
    float* out = (float*)d_out;

    char* ws = (char*)d_ws;
    unsigned short* xb   = (unsigned short*)(ws);                   // 8MB; reused as ctx
    unsigned short* qbuf = (unsigned short*)(ws + (8u << 20));      // 8MB
    unsigned short* kbuf = (unsigned short*)(ws + (16u << 20));     // 8MB
    unsigned short* vtb  = (unsigned short*)(ws + (24u << 20));     // 8MB
    unsigned short* wt   = (unsigned short*)(ws + (32u << 20));     // 6MB
    unsigned short* wot  = (unsigned short*)(ws + (38u << 20));     // 2MB

    conv_x_kernel<<<4096, 256, 0, stream>>>(x, xb);
    transpose_w4<<<dim3(32, 32, 4), dim3(32, 8), 0, stream>>>(
        Wq, Wk, Wv, Wo, wt, wt + (1u << 20), wt + (2u << 20), wot);

    qkv_gemm<<<dim3(24, 32), 256, 0, stream>>>(xb, wt, bq, bk, bv, qbuf, kbuf, vtb);
    attn_kernel<<<dim3(32, 16), 512, 0, stream>>>(qbuf, kbuf, vtb, xb /*ctx*/);
    out_gemm<<<dim3(8, 64), 256, 0, stream>>>(xb, wot, bo, out);
}

// Round 6
// 196.810 us; speedup vs baseline: 1.1316x; 1.1316x over previous
//
#include <hip/hip_runtime.h>
#include <stdint.h>

typedef __attribute__((ext_vector_type(8))) short short8v;    // 8 x bf16 (raw bits)
typedef __attribute__((ext_vector_type(4))) short short4v;    // 4 x bf16
typedef __attribute__((ext_vector_type(4))) float float4v;    // MFMA C/D
typedef __attribute__((ext_vector_type(4))) unsigned short ushort4v;
typedef __attribute__((ext_vector_type(4))) float floatvec4;
typedef __attribute__((ext_vector_type(2))) unsigned int uint2v;

#define DEVI __device__ __forceinline__

// fp32 -> bf16 round-to-nearest-even (finite inputs only)
DEVI unsigned short f2bf(float f) {
    unsigned int u = __builtin_bit_cast(unsigned int, f);
    u += 0x7FFFu + ((u >> 16) & 1u);
    return (unsigned short)(u >> 16);
}

// pack 2 fp32 -> 2 bf16 in one u32 (low = a)
DEVI unsigned int pk2bf(float a, float b) {
#if defined(__has_builtin) && __has_builtin(__builtin_amdgcn_cvt_pk_bf16_f32)
    auto r = __builtin_amdgcn_cvt_pk_bf16_f32(a, b);
    unsigned int u;
    __builtin_memcpy(&u, &r, 4);
    return u;
#else
    return (unsigned int)f2bf(a) | ((unsigned int)f2bf(b) << 16);
#endif
}

DEVI float ex2(float x) {
#if defined(__has_builtin) && __has_builtin(__builtin_amdgcn_exp2f)
    return __builtin_amdgcn_exp2f(x);
#else
    return __builtin_exp2f(x);
#endif
}

typedef __attribute__((address_space(1))) void GV;
typedef __attribute__((address_space(3))) void LV;
// async global->LDS, 16B per lane; LDS dest = wave-uniform base + lane*16
DEVI void gl2lds16(const void* g, void* l) {
    __builtin_amdgcn_global_load_lds((GV*)g, (LV*)l, 16, 0, 0);
}

// ---------------------------------------------------------------------------
// Fused prep: blocks 0..4095 convert x fp32->bf16 (4 el/thread);
// blocks 4096..8191 transpose the 4 weight matrices (fp32 [k][n] -> bf16 [n][k]).
__global__ void prep_kernel(const float* __restrict__ x, unsigned short* __restrict__ xb,
                            const float* __restrict__ W0, const float* __restrict__ W1,
                            const float* __restrict__ W2, const float* __restrict__ W3,
                            unsigned short* __restrict__ D0, unsigned short* __restrict__ D1,
                            unsigned short* __restrict__ D2, unsigned short* __restrict__ D3) {
    const int bid = blockIdx.x, tid = threadIdx.x;
    if (bid < 4096) {
        const int i = (bid * 256 + tid) * 4;
        const floatvec4 v = *(const floatvec4*)&x[i];
        ushort4v o;
#pragma unroll
        for (int r = 0; r < 4; r++) o[r] = f2bf(v[r]);
        *(ushort4v*)&xb[i] = o;
        return;
    }
    __shared__ float t[32][33];
    const int tcode = bid - 4096;
    const int z = tcode >> 10, rem = tcode & 1023;
    const int by = rem >> 5, bx = rem & 31;
    const int tx = tid & 31, ty = tid >> 5;  // (32,8)
    const float* W = (z == 0) ? W0 : (z == 1) ? W1 : (z == 2) ? W2 : W3;
    unsigned short* D = (z == 0) ? D0 : (z == 1) ? D1 : (z == 2) ? D2 : D3;
#pragma unroll
    for (int i = 0; i < 4; i++)
        t[ty + i * 8][tx] = W[(size_t)(by * 32 + ty + i * 8) * 1024 + bx * 32 + tx];
    __syncthreads();
#pragma unroll
    for (int i = 0; i < 4; i++)
        D[(size_t)(bx * 32 + ty + i * 8) * 1024 + by * 32 + tx] = f2bf(t[tx][ty + i * 8]);
}

// ---------------------------------------------------------------------------
// Fused QKV GEMM, BK=64: C[4096 tok][1024] = Xbf @ W{q,k,v}t^T (+bias).
// LDS tiles 128x64 bf16 (16 KB each), granule(8sh=16B) swizzle ^(row&7).
// 16 k-iters, 32 MFMA per barrier-pair.
__global__ __launch_bounds__(256, 3) void qkv_gemm(
    const unsigned short* __restrict__ X, const unsigned short* __restrict__ Wt,
    const float* __restrict__ bq, const float* __restrict__ bk, const float* __restrict__ bv,
    unsigned short* __restrict__ qb, unsigned short* __restrict__ kb,
    unsigned short* __restrict__ vtb)
{
    __shared__ __align__(16) unsigned short As[128 * 64];
    __shared__ __align__(16) unsigned short Bs[128 * 64];
    const int tid = threadIdx.x, lane = tid & 63, wv = tid >> 6;
    const int quad = lane >> 4, l16 = lane & 15;
    const int w = blockIdx.x >> 3;
    const int n0 = (blockIdx.x & 7) * 128;
    const int row0 = blockIdx.y * 128;
    const unsigned short* Wsel = Wt + (size_t)w * (1024 * 1024);

    // staging: chunk = 8 rows x 128B; lane -> row = lane>>3, granule = lane&7
    const int srow = lane >> 3;
    const int qsc = ((lane & 7) ^ (lane >> 3 & 7)) * 8;  // data granule for phys slot
    const int fsw = l16 & 7;                              // frag-read swizzle (row&7)
    const int wm = (wv >> 1) * 64, wn = (wv & 1) * 64;

    float4v acc[4][4];
#pragma unroll
    for (int i = 0; i < 4; i++)
#pragma unroll
        for (int j = 0; j < 4; j++) acc[i][j] = (float4v){0.f, 0.f, 0.f, 0.f};

    for (int k0 = 0; k0 < 1024; k0 += 64) {
        __syncthreads();
#pragma unroll
        for (int i = 0; i < 4; i++) {
            const int c = wv * 4 + i;  // 16 chunks x 8 rows
            gl2lds16(X + (size_t)(row0 + c * 8 + srow) * 1024 + k0 + qsc, As + c * 512);
            gl2lds16(Wsel + (size_t)(n0 + c * 8 + srow) * 1024 + k0 + qsc, Bs + c * 512);
        }
        __syncthreads();
#pragma unroll
        for (int kc = 0; kc < 2; kc++) {
            const int sl = (((kc * 4 + quad) ^ fsw) * 8);
            short8v a[4], b[4];
#pragma unroll
            for (int mt = 0; mt < 4; mt++)
                a[mt] = *(const short8v*)&As[(wm + mt * 16 + l16) * 64 + sl];
#pragma unroll
            for (int nt = 0; nt < 4; nt++)
                b[nt] = *(const short8v*)&Bs[(wn + nt * 16 + l16) * 64 + sl];
#pragma unroll
            for (int mt = 0; mt < 4; mt++)
#pragma unroll
                for (int nt = 0; nt < 4; nt++)
                    acc[mt][nt] = __builtin_amdgcn_mfma_f32_16x16x32_bf16(a[mt], b[nt], acc[mt][nt], 0, 0, 0);
        }
    }

    const float* bias = (w == 0) ? bq : (w == 1) ? bk : bv;
    // q scale: 1/sqrt(64) * log2(e) -> attention uses exp2 with no max-subtract
    const float scl = (w == 0) ? 0.18033688011112042f : 1.0f;
#pragma unroll
    for (int nt = 0; nt < 4; nt++) {
        const int col = n0 + wn + nt * 16 + l16;
        const float bb = bias[col];
        const int h = col >> 6, hd = col & 63;
#pragma unroll
        for (int mt = 0; mt < 4; mt++) {
            const int tok0 = row0 + wm + mt * 16 + quad * 4;
            const int b_ = tok0 >> 11, s0 = tok0 & 2047;
            if (w == 2) {
                ushort4v pk;
#pragma unroll
                for (int r = 0; r < 4; r++) pk[r] = f2bf(acc[mt][nt][r] + bb);
                *(ushort4v*)&vtb[(((size_t)b_ * 16 + h) * 64 + hd) * 2048 + s0] = pk;
            } else {
                unsigned short* dst = (w == 0) ? qb : kb;
#pragma unroll
                for (int r = 0; r < 4; r++)
                    dst[(((size_t)b_ * 16 + h) * 2048 + (s0 + r)) * 64 + hd] =
                        f2bf((acc[mt][nt][r] + bb) * scl);
            }
        }
    }
}

// ---------------------------------------------------------------------------
// Flash attention, S^T formulation, whole-tile S phase, ONE lgkm drain/tile.
// 256 threads = 4 waves; wave owns 32 queries. No max-subtract (scores carry
// log2e/8 from qkv epilogue): p = exp2(s).
// Kt: [128 key][64 hd] granule(8sh) swizzle ^(row&7).
// Vt: [64 hd][128 key] granule(8sh) swizzle ^(row&15).
// Pb: per-wave [32 q][128 key]; chunk = 4 shorts (8B). Chunk swizzle
//   c_phys = c ^ (row&15): row stride 256B == 0 mod 32 banks, so the full
//   4-bit row XOR is needed; gives exactly 2 dwords/bank for both
//   ds_write_b64 (fixed mt,nt) and ds_read_b64 (fixed kc,nt,t) instrs.
__global__ __launch_bounds__(256, 2) void attn_kernel(
    const unsigned short* __restrict__ qb, const unsigned short* __restrict__ kb,
    const unsigned short* __restrict__ vtb, unsigned short* __restrict__ ctxb)
{
    __shared__ __align__(16) unsigned short Kt[128 * 64];
    __shared__ __align__(16) unsigned short Vt[64 * 128];
    __shared__ __align__(16) unsigned short Pb[4][32 * 128];
    const int tid = threadIdx.x, lane = tid & 63, wv = tid >> 6;
    const int quad = lane >> 4, l16 = lane & 15;
    const int bh = blockIdx.x, qt = blockIdx.y;
    const size_t boff = (size_t)bh * (2048 * 64);
    const unsigned short* qp = qb + boff;
    const unsigned short* kp = kb + boff;
    const unsigned short* vp = vtb + boff;
    const int q0 = qt * 128 + wv * 32;

    // Q fragments (B operand): [q=l16][hd=quad*8..], register-resident
    short8v qf[2][2];
#pragma unroll
    for (int nt = 0; nt < 2; nt++)
#pragma unroll
        for (int kc = 0; kc < 2; kc++)
            qf[nt][kc] = *(const short8v*)&qp[(size_t)(q0 + nt * 16 + l16) * 64 + kc * 32 + quad * 8];

    float4v accO[2][4];
#pragma unroll
    for (int nt = 0; nt < 2; nt++)
#pragma unroll
        for (int ht = 0; ht < 4; ht++) accO[nt][ht] = (float4v){0.f, 0.f, 0.f, 0.f};
    float lsum[2] = {0.f, 0.f};

    // staging lane mapping (verified R1-R4)
    const int krow = lane >> 3;
    const int kg = (lane & 7) ^ (lane >> 3);
    const int vrow = lane >> 4;
    const int rsw = l16 & 7;

    // Kt A-frag read bases (row=key=mt*16+l16)
    const int ktb0 = l16 * 64 + ((quad ^ rsw) * 8);
    const int ktb1 = l16 * 64 + (((4 + quad) ^ rsw) * 8);
    // Vt B-frag read base: granule (kc*4+quad) ^ l16
    const int vrb = l16 * 128 + ((quad ^ (l16 & 3)) * 8);
    const int l12e = (l16 & 12) * 8;
    // Pb: write chunk c = mt*4+quad; read chunks c = kc*8+quad*2+{0,1}.
    // Both at physical chunk c ^ l16, offset (c^l16)*4 shorts within row l16.
    const int prow = l16 * 128;

    for (int kt0 = 0; kt0 < 2048; kt0 += 128) {
        __syncthreads();
#pragma unroll
        for (int i = 0; i < 4; i++) {
            const int c = wv * 4 + i;
            gl2lds16(kp + (size_t)(kt0 + c * 8 + krow) * 64 + kg * 8, Kt + c * 512);
            const int vr = c * 4 + vrow;
            const int vg = (lane & 15) ^ (vr & 15);
            gl2lds16(vp + (size_t)vr * 2048 + kt0 + vg * 8, Vt + c * 512);
        }
        __syncthreads();

        // ---- S phase: all 128 keys; exp2 fused; P -> per-wave LDS (b64 writes)
#pragma unroll
        for (int mt = 0; mt < 8; mt++) {
            const short8v a0 = *(const short8v*)&Kt[ktb0 + mt * 1024];
            const short8v a1 = *(const short8v*)&Kt[ktb1 + mt * 1024];
            const int pwo = prow + (((mt * 4 + quad) ^ l16) * 4);
#pragma unroll
            for (int nt = 0; nt < 2; nt++) {
                float4v z = (float4v){0.f, 0.f, 0.f, 0.f};
                z = __builtin_amdgcn_mfma_f32_16x16x32_bf16(a0, qf[nt][0], z, 0, 0, 0);
                z = __builtin_amdgcn_mfma_f32_16x16x32_bf16(a1, qf[nt][1], z, 0, 0, 0);
                const float p0 = ex2(z[0]), p1 = ex2(z[1]);
                const float p2 = ex2(z[2]), p3 = ex2(z[3]);
                lsum[nt] += (p0 + p1) + (p2 + p3);
                *(uint2v*)&Pb[wv][pwo + nt * 2048] = (uint2v){pk2bf(p0, p1), pk2bf(p2, p3)};
            }
        }
        asm volatile("s_waitcnt lgkmcnt(0)" ::: "memory");  // own P writes visible

        // ---- PV: O += P V  (A = P from Pb via 2x b64, B = V^T from Vt)
#pragma unroll
        for (int kc = 0; kc < 4; kc++) {
            const int roff = (kc * 32) ^ l12e;
            short8v bvv[4];
#pragma unroll
            for (int ht = 0; ht < 4; ht++)
                bvv[ht] = *(const short8v*)&Vt[vrb + roff + ht * 2048];
            const int c0 = prow + (((kc * 8 + quad * 2) ^ l16) * 4);
            const int c1 = prow + (((kc * 8 + quad * 2 + 1) ^ l16) * 4);
#pragma unroll
            for (int nt = 0; nt < 2; nt++) {
                const short4v d0 = *(const short4v*)&Pb[wv][c0 + nt * 2048];
                const short4v d1 = *(const short4v*)&Pb[wv][c1 + nt * 2048];
                const short8v ap = __builtin_shufflevector(d0, d1, 0, 1, 2, 3, 4, 5, 6, 7);
#pragma unroll
                for (int ht = 0; ht < 4; ht++)
                    accO[nt][ht] = __builtin_amdgcn_mfma_f32_16x16x32_bf16(ap, bvv[ht], accO[nt][ht], 0, 0, 0);
            }
        }
    }

    // reduce row-sums across quads (query = l16 per nt)
#pragma unroll
    for (int nt = 0; nt < 2; nt++) {
        lsum[nt] += __shfl_xor(lsum[nt], 16);
        lsum[nt] += __shfl_xor(lsum[nt], 32);
    }

    const int b_ = bh >> 4, h = bh & 15;
#pragma unroll
    for (int nt = 0; nt < 2; nt++)
#pragma unroll
        for (int r = 0; r < 4; r++) {
            const int s = q0 + nt * 16 + quad * 4 + r;
            const float inv = 1.0f / __shfl(lsum[nt], quad * 4 + r);
#pragma unroll
            for (int ht = 0; ht < 4; ht++) {
                const int hd = ht * 16 + l16;
                ctxb[((size_t)(b_ * 2048 + s)) * 1024 + h * 64 + hd] = f2bf(accO[nt][ht][r] * inv);
            }
        }
}

// ---------------------------------------------------------------------------
// out = ctx @ Wo + bo (fp32 output). 64x64 tile, 4 blocks/CU, grid 1024.
__global__ __launch_bounds__(256, 4) void out_gemm(
    const unsigned short* __restrict__ ctx, const unsigned short* __restrict__ Wot,
    const float* __restrict__ bo, float* __restrict__ out)
{
    __shared__ __align__(16) unsigned short As[64 * 32];
    __shared__ __align__(16) unsigned short Bs[64 * 32];
    const int tid = threadIdx.x, lane = tid & 63, wv = tid >> 6;
    const int quad = lane >> 4, l16 = lane & 15;
    const int n0 = blockIdx.x * 64;
    const int row0 = blockIdx.y * 64;

    const int srow = lane >> 2;
    const int sg = (lane & 3) ^ ((lane >> 2) & 3) ^ ((lane >> 4) & 3);
    const int scol = sg * 8;
    const int fsw = (l16 & 3) ^ ((l16 >> 2) & 3);
    const int wm = (wv & 1) * 32, wn = (wv >> 1) * 32;

    float4v acc[2][2];
#pragma unroll
    for (int i = 0; i < 2; i++)
#pragma unroll
        for (int j = 0; j < 2; j++) acc[i][j] = (float4v){0.f, 0.f, 0.f, 0.f};

    for (int k0 = 0; k0 < 1024; k0 += 32) {
        __syncthreads();
#pragma unroll
        for (int i = 0; i < 2; i++) {
            const int idx = wv * 2 + i;  // 0..7: 4 As chunks then 4 Bs chunks
            if (idx < 4)
                gl2lds16(ctx + (size_t)(row0 + idx * 16 + srow) * 1024 + k0 + scol, As + idx * 512);
            else
                gl2lds16(Wot + (size_t)(n0 + (idx - 4) * 16 + srow) * 1024 + k0 + scol,
                         Bs + (idx - 4) * 512);
        }
        __syncthreads();
        short8v a[2], b[2];
#pragma unroll
        for (int mt = 0; mt < 2; mt++)
            a[mt] = *(const short8v*)&As[(wm + mt * 16 + l16) * 32 + ((quad ^ fsw) * 8)];
#pragma unroll
        for (int nt = 0; nt < 2; nt++)
            b[nt] = *(const short8v*)&Bs[(wn + nt * 16 + l16) * 32 + ((quad ^ fsw) * 8)];
#pragma unroll
        for (int mt = 0; mt < 2; mt++)
#pragma unroll
            for (int nt = 0; nt < 2; nt++)
                acc[mt][nt] = __builtin_amdgcn_mfma_f32_16x16x32_bf16(a[mt], b[nt], acc[mt][nt], 0, 0, 0);
    }

#pragma unroll
    for (int nt = 0; nt < 2; nt++) {
        const int col = n0 + wn + nt * 16 + l16;
        const float bb = bo[col];
#pragma unroll
        for (int mt = 0; mt < 2; mt++) {
            const int tok0 = row0 + wm + mt * 16 + quad * 4;
#pragma unroll
            for (int r = 0; r < 4; r++)
                out[(size_t)(tok0 + r) * 1024 + col] = acc[mt][nt][r] + bb;
        }
    }
}

// ---------------------------------------------------------------------------
extern "C" void kernel_launch(void* const* d_in, const int* in_sizes, int n_in,
                              void* d_out, int out_size, void* d_ws, size_t ws_size,
                              hipStream_t stream) {
    const float* x  = (const float*)d_in[0];
    const float* Wq = (const float*)d_in[1];
    const float* bq = (const float*)d_in[2];
    const float* Wk = (const float*)d_in[3];
    const float* bk = (const float*)d_in[4];
    const float* Wv = (const float*)d_in[5];
    const float* bv = (const float*)d_in[6];
    const float* Wo = (const float*)d_in[7];
    const float* bo = (const float*)d_in[8];
    float* out = (float*)d_out;

    char* ws = (char*)d_ws;
    unsigned short* xb   = (unsigned short*)(ws);                   // 8MB; reused as ctx
    unsigned short* qbuf = (unsigned short*)(ws + (8u << 20));      // 8MB
    unsigned short* kbuf = (unsigned short*)(ws + (16u << 20));     // 8MB
    unsigned short* vtb  = (unsigned short*)(ws + (24u << 20));     // 8MB
    unsigned short* wt   = (unsigned short*)(ws + (32u << 20));     // 6MB
    unsigned short* wot  = (unsigned short*)(ws + (38u << 20));     // 2MB

    prep_kernel<<<8192, 256, 0, stream>>>(x, xb, Wq, Wk, Wv, Wo,
                                          wt, wt + (1u << 20), wt + (2u << 20), wot);
    qkv_gemm<<<dim3(24, 32), 256, 0, stream>>>(xb, wt, bq, bk, bv, qbuf, kbuf, vtb);
    attn_kernel<<<dim3(32, 16), 256, 0, stream>>>(qbuf, kbuf, vtb, xb /*ctx*/);
    out_gemm<<<dim3(16, 64), 256, 0, stream>>>(xb, wot, bo, out);
}

// Round 7
// 189.601 us; speedup vs baseline: 1.1746x; 1.0380x over previous
//
#include <hip/hip_runtime.h>
#include <stdint.h>

typedef __attribute__((ext_vector_type(8))) short short8v;    // 8 x bf16 (raw bits)
typedef __attribute__((ext_vector_type(4))) short short4v;    // 4 x bf16
typedef __attribute__((ext_vector_type(4))) float float4v;    // MFMA C/D
typedef __attribute__((ext_vector_type(4))) unsigned short ushort4v;
typedef __attribute__((ext_vector_type(4))) float floatvec4;
typedef __attribute__((ext_vector_type(2))) unsigned int uint2v;

#define DEVI __device__ __forceinline__

// fp32 -> bf16 round-to-nearest-even (finite inputs only)
DEVI unsigned short f2bf(float f) {
    unsigned int u = __builtin_bit_cast(unsigned int, f);
    u += 0x7FFFu + ((u >> 16) & 1u);
    return (unsigned short)(u >> 16);
}

// pack 2 fp32 -> 2 bf16 in one u32 (low = a)
DEVI unsigned int pk2bf(float a, float b) {
#if defined(__has_builtin) && __has_builtin(__builtin_amdgcn_cvt_pk_bf16_f32)
    auto r = __builtin_amdgcn_cvt_pk_bf16_f32(a, b);
    unsigned int u;
    __builtin_memcpy(&u, &r, 4);
    return u;
#else
    return (unsigned int)f2bf(a) | ((unsigned int)f2bf(b) << 16);
#endif
}

DEVI float ex2(float x) {
#if defined(__has_builtin) && __has_builtin(__builtin_amdgcn_exp2f)
    return __builtin_amdgcn_exp2f(x);
#else
    return __builtin_exp2f(x);
#endif
}

typedef __attribute__((address_space(1))) void GV;
typedef __attribute__((address_space(3))) void LV;
// async global->LDS, 16B per lane; LDS dest = wave-uniform base + lane*16
DEVI void gl2lds16(const void* g, void* l) {
    __builtin_amdgcn_global_load_lds((GV*)g, (LV*)l, 16, 0, 0);
}

// ---------------------------------------------------------------------------
// Fused prep: blocks 0..4095 convert x fp32->bf16 (4 el/thread);
// blocks 4096..8191 transpose the 4 weight matrices (fp32 [k][n] -> bf16 [n][k]).
__global__ void prep_kernel(const float* __restrict__ x, unsigned short* __restrict__ xb,
                            const float* __restrict__ W0, const float* __restrict__ W1,
                            const float* __restrict__ W2, const float* __restrict__ W3,
                            unsigned short* __restrict__ D0, unsigned short* __restrict__ D1,
                            unsigned short* __restrict__ D2, unsigned short* __restrict__ D3) {
    const int bid = blockIdx.x, tid = threadIdx.x;
    if (bid < 4096) {
        const int i = (bid * 256 + tid) * 4;
        const floatvec4 v = *(const floatvec4*)&x[i];
        ushort4v o;
#pragma unroll
        for (int r = 0; r < 4; r++) o[r] = f2bf(v[r]);
        *(ushort4v*)&xb[i] = o;
        return;
    }
    __shared__ float t[32][33];
    const int tcode = bid - 4096;
    const int z = tcode >> 10, rem = tcode & 1023;
    const int by = rem >> 5, bx = rem & 31;
    const int tx = tid & 31, ty = tid >> 5;  // (32,8)
    const float* W = (z == 0) ? W0 : (z == 1) ? W1 : (z == 2) ? W2 : W3;
    unsigned short* D = (z == 0) ? D0 : (z == 1) ? D1 : (z == 2) ? D2 : D3;
#pragma unroll
    for (int i = 0; i < 4; i++)
        t[ty + i * 8][tx] = W[(size_t)(by * 32 + ty + i * 8) * 1024 + bx * 32 + tx];
    __syncthreads();
#pragma unroll
    for (int i = 0; i < 4; i++)
        D[(size_t)(bx * 32 + ty + i * 8) * 1024 + by * 32 + tx] = f2bf(t[tx][ty + i * 8]);
}

// ---------------------------------------------------------------------------
// Fused QKV GEMM, BK=64: C[4096 tok][1024] = Xbf @ W{q,k,v}t^T (+bias).
// LDS tiles 128x64 bf16 (16 KB each), granule(8sh=16B) swizzle ^(row&7).
// 16 k-iters, 32 MFMA per barrier-pair.
__global__ __launch_bounds__(256, 3) void qkv_gemm(
    const unsigned short* __restrict__ X, const unsigned short* __restrict__ Wt,
    const float* __restrict__ bq, const float* __restrict__ bk, const float* __restrict__ bv,
    unsigned short* __restrict__ qb, unsigned short* __restrict__ kb,
    unsigned short* __restrict__ vtb)
{
    __shared__ __align__(16) unsigned short As[128 * 64];
    __shared__ __align__(16) unsigned short Bs[128 * 64];
    const int tid = threadIdx.x, lane = tid & 63, wv = tid >> 6;
    const int quad = lane >> 4, l16 = lane & 15;
    const int w = blockIdx.x >> 3;
    const int n0 = (blockIdx.x & 7) * 128;
    const int row0 = blockIdx.y * 128;
    const unsigned short* Wsel = Wt + (size_t)w * (1024 * 1024);

    // staging: chunk = 8 rows x 128B; lane -> row = lane>>3, granule = lane&7
    const int srow = lane >> 3;
    const int qsc = ((lane & 7) ^ (lane >> 3 & 7)) * 8;  // data granule for phys slot
    const int fsw = l16 & 7;                              // frag-read swizzle (row&7)
    const int wm = (wv >> 1) * 64, wn = (wv & 1) * 64;

    float4v acc[4][4];
#pragma unroll
    for (int i = 0; i < 4; i++)
#pragma unroll
        for (int j = 0; j < 4; j++) acc[i][j] = (float4v){0.f, 0.f, 0.f, 0.f};

    for (int k0 = 0; k0 < 1024; k0 += 64) {
        __syncthreads();
#pragma unroll
        for (int i = 0; i < 4; i++) {
            const int c = wv * 4 + i;  // 16 chunks x 8 rows
            gl2lds16(X + (size_t)(row0 + c * 8 + srow) * 1024 + k0 + qsc, As + c * 512);
            gl2lds16(Wsel + (size_t)(n0 + c * 8 + srow) * 1024 + k0 + qsc, Bs + c * 512);
        }
        __syncthreads();
#pragma unroll
        for (int kc = 0; kc < 2; kc++) {
            const int sl = (((kc * 4 + quad) ^ fsw) * 8);
            short8v a[4], b[4];
#pragma unroll
            for (int mt = 0; mt < 4; mt++)
                a[mt] = *(const short8v*)&As[(wm + mt * 16 + l16) * 64 + sl];
#pragma unroll
            for (int nt = 0; nt < 4; nt++)
                b[nt] = *(const short8v*)&Bs[(wn + nt * 16 + l16) * 64 + sl];
#pragma unroll
            for (int mt = 0; mt < 4; mt++)
#pragma unroll
                for (int nt = 0; nt < 4; nt++)
                    acc[mt][nt] = __builtin_amdgcn_mfma_f32_16x16x32_bf16(a[mt], b[nt], acc[mt][nt], 0, 0, 0);
        }
    }

    const float* bias = (w == 0) ? bq : (w == 1) ? bk : bv;
    // q scale: 1/sqrt(64) * log2(e) -> attention uses exp2 with no max-subtract
    const float scl = (w == 0) ? 0.18033688011112042f : 1.0f;
#pragma unroll
    for (int nt = 0; nt < 4; nt++) {
        const int col = n0 + wn + nt * 16 + l16;
        const float bb = bias[col];
        const int h = col >> 6, hd = col & 63;
#pragma unroll
        for (int mt = 0; mt < 4; mt++) {
            const int tok0 = row0 + wm + mt * 16 + quad * 4;
            const int b_ = tok0 >> 11, s0 = tok0 & 2047;
            if (w == 2) {
                ushort4v pk;
#pragma unroll
                for (int r = 0; r < 4; r++) pk[r] = f2bf(acc[mt][nt][r] + bb);
                *(ushort4v*)&vtb[(((size_t)b_ * 16 + h) * 64 + hd) * 2048 + s0] = pk;
            } else {
                unsigned short* dst = (w == 0) ? qb : kb;
#pragma unroll
                for (int r = 0; r < 4; r++)
                    dst[(((size_t)b_ * 16 + h) * 2048 + (s0 + r)) * 64 + hd] =
                        f2bf((acc[mt][nt][r] + bb) * scl);
            }
        }
    }
}

// ---------------------------------------------------------------------------
// Flash attention, S^T formulation, whole-tile S phase, ONE lgkm drain/tile.
// (verified R6 kernel — unchanged)
__global__ __launch_bounds__(256, 2) void attn_kernel(
    const unsigned short* __restrict__ qb, const unsigned short* __restrict__ kb,
    const unsigned short* __restrict__ vtb, unsigned short* __restrict__ ctxb)
{
    __shared__ __align__(16) unsigned short Kt[128 * 64];
    __shared__ __align__(16) unsigned short Vt[64 * 128];
    __shared__ __align__(16) unsigned short Pb[4][32 * 128];
    const int tid = threadIdx.x, lane = tid & 63, wv = tid >> 6;
    const int quad = lane >> 4, l16 = lane & 15;
    const int bh = blockIdx.x, qt = blockIdx.y;
    const size_t boff = (size_t)bh * (2048 * 64);
    const unsigned short* qp = qb + boff;
    const unsigned short* kp = kb + boff;
    const unsigned short* vp = vtb + boff;
    const int q0 = qt * 128 + wv * 32;

    // Q fragments (B operand): [q=l16][hd=quad*8..], register-resident
    short8v qf[2][2];
#pragma unroll
    for (int nt = 0; nt < 2; nt++)
#pragma unroll
        for (int kc = 0; kc < 2; kc++)
            qf[nt][kc] = *(const short8v*)&qp[(size_t)(q0 + nt * 16 + l16) * 64 + kc * 32 + quad * 8];

    float4v accO[2][4];
#pragma unroll
    for (int nt = 0; nt < 2; nt++)
#pragma unroll
        for (int ht = 0; ht < 4; ht++) accO[nt][ht] = (float4v){0.f, 0.f, 0.f, 0.f};
    float lsum[2] = {0.f, 0.f};

    // staging lane mapping (verified R1-R6)
    const int krow = lane >> 3;
    const int kg = (lane & 7) ^ (lane >> 3);
    const int vrow = lane >> 4;
    const int rsw = l16 & 7;

    // Kt A-frag read bases (row=key=mt*16+l16)
    const int ktb0 = l16 * 64 + ((quad ^ rsw) * 8);
    const int ktb1 = l16 * 64 + (((4 + quad) ^ rsw) * 8);
    // Vt B-frag read base: granule (kc*4+quad) ^ l16
    const int vrb = l16 * 128 + ((quad ^ (l16 & 3)) * 8);
    const int l12e = (l16 & 12) * 8;
    // Pb: write chunk c = mt*4+quad; read chunks c = kc*8+quad*2+{0,1}.
    // Both at physical chunk c ^ l16, offset (c^l16)*4 shorts within row l16.
    const int prow = l16 * 128;

    for (int kt0 = 0; kt0 < 2048; kt0 += 128) {
        __syncthreads();
#pragma unroll
        for (int i = 0; i < 4; i++) {
            const int c = wv * 4 + i;
            gl2lds16(kp + (size_t)(kt0 + c * 8 + krow) * 64 + kg * 8, Kt + c * 512);
            const int vr = c * 4 + vrow;
            const int vg = (lane & 15) ^ (vr & 15);
            gl2lds16(vp + (size_t)vr * 2048 + kt0 + vg * 8, Vt + c * 512);
        }
        __syncthreads();

        // ---- S phase: all 128 keys; exp2 fused; P -> per-wave LDS (b64 writes)
#pragma unroll
        for (int mt = 0; mt < 8; mt++) {
            const short8v a0 = *(const short8v*)&Kt[ktb0 + mt * 1024];
            const short8v a1 = *(const short8v*)&Kt[ktb1 + mt * 1024];
            const int pwo = prow + (((mt * 4 + quad) ^ l16) * 4);
#pragma unroll
            for (int nt = 0; nt < 2; nt++) {
                float4v z = (float4v){0.f, 0.f, 0.f, 0.f};
                z = __builtin_amdgcn_mfma_f32_16x16x32_bf16(a0, qf[nt][0], z, 0, 0, 0);
                z = __builtin_amdgcn_mfma_f32_16x16x32_bf16(a1, qf[nt][1], z, 0, 0, 0);
                const float p0 = ex2(z[0]), p1 = ex2(z[1]);
                const float p2 = ex2(z[2]), p3 = ex2(z[3]);
                lsum[nt] += (p0 + p1) + (p2 + p3);
                *(uint2v*)&Pb[wv][pwo + nt * 2048] = (uint2v){pk2bf(p0, p1), pk2bf(p2, p3)};
            }
        }
        asm volatile("s_waitcnt lgkmcnt(0)" ::: "memory");  // own P writes visible

        // ---- PV: O += P V  (A = P from Pb via 2x b64, B = V^T from Vt)
#pragma unroll
        for (int kc = 0; kc < 4; kc++) {
            const int roff = (kc * 32) ^ l12e;
            short8v bvv[4];
#pragma unroll
            for (int ht = 0; ht < 4; ht++)
                bvv[ht] = *(const short8v*)&Vt[vrb + roff + ht * 2048];
            const int c0 = prow + (((kc * 8 + quad * 2) ^ l16) * 4);
            const int c1 = prow + (((kc * 8 + quad * 2 + 1) ^ l16) * 4);
#pragma unroll
            for (int nt = 0; nt < 2; nt++) {
                const short4v d0 = *(const short4v*)&Pb[wv][c0 + nt * 2048];
                const short4v d1 = *(const short4v*)&Pb[wv][c1 + nt * 2048];
                const short8v ap = __builtin_shufflevector(d0, d1, 0, 1, 2, 3, 4, 5, 6, 7);
#pragma unroll
                for (int ht = 0; ht < 4; ht++)
                    accO[nt][ht] = __builtin_amdgcn_mfma_f32_16x16x32_bf16(ap, bvv[ht], accO[nt][ht], 0, 0, 0);
            }
        }
    }

    // reduce row-sums across quads (query = l16 per nt)
#pragma unroll
    for (int nt = 0; nt < 2; nt++) {
        lsum[nt] += __shfl_xor(lsum[nt], 16);
        lsum[nt] += __shfl_xor(lsum[nt], 32);
    }

    const int b_ = bh >> 4, h = bh & 15;
#pragma unroll
    for (int nt = 0; nt < 2; nt++)
#pragma unroll
        for (int r = 0; r < 4; r++) {
            const int s = q0 + nt * 16 + quad * 4 + r;
            const float inv = 1.0f / __shfl(lsum[nt], quad * 4 + r);
#pragma unroll
            for (int ht = 0; ht < 4; ht++) {
                const int hd = ht * 16 + l16;
                ctxb[((size_t)(b_ * 2048 + s)) * 1024 + h * 64 + hd] = f2bf(accO[nt][ht][r] * inv);
            }
        }
}

// ---------------------------------------------------------------------------
// out = ctx @ Wo + bo (fp32 output). 128m x 64n tile, BK=64 (qkv-style
// staging: chunk = 8 rows x 128B, granule swizzle ^(row&7)). Wave = 64m x 32n,
// 16 MFMA per barrier-pair, 16 k-iters. Grid (16,32) = 512 -> 2 blocks/CU.
__global__ __launch_bounds__(256, 2) void out_gemm(
    const unsigned short* __restrict__ ctx, const unsigned short* __restrict__ Wot,
    const float* __restrict__ bo, float* __restrict__ out)
{
    __shared__ __align__(16) unsigned short As[128 * 64];
    __shared__ __align__(16) unsigned short Bs[64 * 64];
    const int tid = threadIdx.x, lane = tid & 63, wv = tid >> 6;
    const int quad = lane >> 4, l16 = lane & 15;
    const int n0 = blockIdx.x * 64;
    const int row0 = blockIdx.y * 128;

    const int srow = lane >> 3;
    const int qsc = ((lane & 7) ^ (lane >> 3 & 7)) * 8;
    const int fsw = l16 & 7;
    const int wm = (wv & 1) * 64, wn = (wv >> 1) * 32;

    float4v acc[4][2];
#pragma unroll
    for (int i = 0; i < 4; i++)
#pragma unroll
        for (int j = 0; j < 2; j++) acc[i][j] = (float4v){0.f, 0.f, 0.f, 0.f};

    for (int k0 = 0; k0 < 1024; k0 += 64) {
        __syncthreads();
#pragma unroll
        for (int i = 0; i < 6; i++) {
            const int c = wv * 6 + i;  // 0..23: 16 As chunks then 8 Bs chunks
            if (c < 16)
                gl2lds16(ctx + (size_t)(row0 + c * 8 + srow) * 1024 + k0 + qsc, As + c * 512);
            else
                gl2lds16(Wot + (size_t)(n0 + (c - 16) * 8 + srow) * 1024 + k0 + qsc,
                         Bs + (c - 16) * 512);
        }
        __syncthreads();
#pragma unroll
        for (int kc = 0; kc < 2; kc++) {
            const int sl = (((kc * 4 + quad) ^ fsw) * 8);
            short8v a[4], b[2];
#pragma unroll
            for (int mt = 0; mt < 4; mt++)
                a[mt] = *(const short8v*)&As[(wm + mt * 16 + l16) * 64 + sl];
#pragma unroll
            for (int nt = 0; nt < 2; nt++)
                b[nt] = *(const short8v*)&Bs[(wn + nt * 16 + l16) * 64 + sl];
#pragma unroll
            for (int mt = 0; mt < 4; mt++)
#pragma unroll
                for (int nt = 0; nt < 2; nt++)
                    acc[mt][nt] = __builtin_amdgcn_mfma_f32_16x16x32_bf16(a[mt], b[nt], acc[mt][nt], 0, 0, 0);
        }
    }

#pragma unroll
    for (int nt = 0; nt < 2; nt++) {
        const int col = n0 + wn + nt * 16 + l16;
        const float bb = bo[col];
#pragma unroll
        for (int mt = 0; mt < 4; mt++) {
            const int tok0 = row0 + wm + mt * 16 + quad * 4;
#pragma unroll
            for (int r = 0; r < 4; r++)
                out[(size_t)(tok0 + r) * 1024 + col] = acc[mt][nt][r] + bb;
        }
    }
}

// ---------------------------------------------------------------------------
extern "C" void kernel_launch(void* const* d_in, const int* in_sizes, int n_in,
                              void* d_out, int out_size, void* d_ws, size_t ws_size,
                              hipStream_t stream) {
    const float* x  = (const float*)d_in[0];
    const float* Wq = (const float*)d_in[1];
    const float* bq = (const float*)d_in[2];
    const float* Wk = (const float*)d_in[3];
    const float* bk = (const float*)d_in[4];
    const float* Wv = (const float*)d_in[5];
    const float* bv = (const float*)d_in[6];
    const float* Wo = (const float*)d_in[7];
    const float* bo = (const float*)d_in[8];
    float* out = (float*)d_out;

    char* ws = (char*)d_ws;
    unsigned short* xb   = (unsigned short*)(ws);                   // 8MB; reused as ctx
    unsigned short* qbuf = (unsigned short*)(ws + (8u << 20));      // 8MB
    unsigned short* kbuf = (unsigned short*)(ws + (16u << 20));     // 8MB
    unsigned short* vtb  = (unsigned short*)(ws + (24u << 20));     // 8MB
    unsigned short* wt   = (unsigned short*)(ws + (32u << 20));     // 6MB
    unsigned short* wot  = (unsigned short*)(ws + (38u << 20));     // 2MB

    prep_kernel<<<8192, 256, 0, stream>>>(x, xb, Wq, Wk, Wv, Wo,
                                          wt, wt + (1u << 20), wt + (2u << 20), wot);
    qkv_gemm<<<dim3(24, 32), 256, 0, stream>>>(xb, wt, bq, bk, bv, qbuf, kbuf, vtb);
    attn_kernel<<<dim3(32, 16), 256, 0, stream>>>(qbuf, kbuf, vtb, xb /*ctx*/);
    out_gemm<<<dim3(16, 32), 256, 0, stream>>>(xb, wot, bo, out);
}